// Round 1
// baseline (202.662 us; speedup 1.0000x reference)
//
#include <hip/hip_runtime.h>

// Bicubic 4x upscale, Keys a=-0.5, jax.image.resize semantics:
// sample_f = (o + 0.5)/4 - 0.5 ; out-of-range taps DROPPED and weights
// renormalized per dimension (NOT clamped).
//
// 4 phases per dim (o = 4*j + r):
//   r=0: t=0.625, base j-2 : [k(1.625), k(0.625), k(0.375), k(1.375)]
//   r=1: t=0.875, base j-2 : [k(1.875), k(0.875), k(0.125), k(1.125)]
//   r=2: t=0.125, base j-1 : mirror of r=1
//   r=3: t=0.375, base j-1 : mirror of r=0
// All weights are exact dyadic rationals below; interior sums are exactly 1.0f.

#define Hin 256
#define Win 256

__global__ __launch_bounds__(256) void cubic_up4(const float* __restrict__ in,
                                                 float* __restrict__ out) {
    const int jx = threadIdx.x;            // input-column tile, 0..255
    const int blk = blockIdx.x;            // (b*3 + c) * 256 + jy
    const int jy = blk & (Hin - 1);
    const int bc = blk >> 8;               // 0..47

    const float* __restrict__ inp = in + (size_t)bc * (Hin * Win);
    float* __restrict__ outp = out + (size_t)bc * ((size_t)Hin * Win * 16);

    // Stage the 5 input rows this block needs (clamped row index only as a
    // dummy value source -- OOB taps get weight 0).
    __shared__ float sv[5][Win];
#pragma unroll
    for (int r = 0; r < 5; ++r) {
        int ry = jy - 2 + r;
        ry = ry < 0 ? 0 : (ry > Hin - 1 ? Hin - 1 : ry);
        sv[r][jx] = inp[ry * Win + jx];
    }
    __syncthreads();

    const float WKc[4][4] = {
        {-0.0439453125f, 0.3896484375f, 0.7275390625f, -0.0732421875f},
        {-0.0068359375f, 0.0908203125f, 0.9638671875f, -0.0478515625f},
        {-0.0478515625f, 0.9638671875f, 0.0908203125f, -0.0068359375f},
        {-0.0732421875f, 0.7275390625f, 0.3896484375f, -0.0439453125f}};

    // Per-phase weights with jax-style drop + renormalize at edges.
    float wx[4][4];
#pragma unroll
    for (int r = 0; r < 4; ++r) {
        float s = 0.f;
#pragma unroll
        for (int t = 0; t < 4; ++t) {
            int c = jx - 2 + (r >> 1) + t;
            float w = (c >= 0 && c < Win) ? WKc[r][t] : 0.f;
            wx[r][t] = w;
            s += w;
        }
        float inv = 1.f / s;
#pragma unroll
        for (int t = 0; t < 4; ++t) wx[r][t] *= inv;
    }
    float wy[4][4];
#pragma unroll
    for (int r = 0; r < 4; ++r) {
        float s = 0.f;
#pragma unroll
        for (int t = 0; t < 4; ++t) {
            int c = jy - 2 + (r >> 1) + t;
            float w = (c >= 0 && c < Hin) ? WKc[r][t] : 0.f;
            wy[r][t] = w;
            s += w;
        }
        float inv = 1.f / s;
#pragma unroll
        for (int t = 0; t < 4; ++t) wy[r][t] *= inv;
    }

    // 5x5 neighborhood from LDS (stride-1 across lanes: conflict-free).
    float v[5][5];
#pragma unroll
    for (int k = 0; k < 5; ++k) {
        int c = jx - 2 + k;
        c = c < 0 ? 0 : (c > Win - 1 ? Win - 1 : c);
#pragma unroll
        for (int r = 0; r < 5; ++r) v[r][k] = sv[r][c];
    }

    // Horizontal pass: h[row][rx]
    float h[5][4];
#pragma unroll
    for (int r = 0; r < 5; ++r) {
#pragma unroll
        for (int rx = 0; rx < 4; ++rx) {
            int o = rx >> 1;
            h[r][rx] = wx[rx][0] * v[r][o] + wx[rx][1] * v[r][o + 1] +
                       wx[rx][2] * v[r][o + 2] + wx[rx][3] * v[r][o + 3];
        }
    }

    // Vertical pass + coalesced float4 stores (4 output rows).
#pragma unroll
    for (int ry = 0; ry < 4; ++ry) {
        int o = ry >> 1;
        float4 res;
        float* rp = (float*)&res;
#pragma unroll
        for (int rx = 0; rx < 4; ++rx) {
            rp[rx] = wy[ry][0] * h[o][rx] + wy[ry][1] * h[o + 1][rx] +
                     wy[ry][2] * h[o + 2][rx] + wy[ry][3] * h[o + 3][rx];
        }
        float4* dst = (float4*)(outp + (size_t)(4 * jy + ry) * (Win * 4) + 4 * jx);
        *dst = res;
    }
}

extern "C" void kernel_launch(void* const* d_in, const int* in_sizes, int n_in,
                              void* d_out, int out_size, void* d_ws, size_t ws_size,
                              hipStream_t stream) {
    const float* x = (const float*)d_in[0];
    float* out = (float*)d_out;
    // 16 batches * 3 channels * 256 input rows = 12288 blocks, 256 threads.
    cubic_up4<<<dim3(16 * 3 * 256), dim3(256), 0, stream>>>(x, out);
}

// Round 2
// 199.869 us; speedup vs baseline: 1.0140x; 1.0140x over previous
//
#include <hip/hip_runtime.h>

// Bicubic 4x upscale, Keys a=-0.5, jax.image.resize semantics:
// sample s = (o+0.5)/4 - 0.5; OOB taps dropped + weights renormalized.
// Phase weights (exact dyadic rationals, interior rows sum to exactly 1.0):
//   r=0: base j-2: [k(1.625), k(0.625), k(0.375), k(1.375)]
//   r=1: base j-2: [k(1.875), k(0.875), k(0.125), k(1.125)]
//   r=2: base j-1: mirror of r=1
//   r=3: base j-1: mirror of r=0
//
// Block = (bc, jy4): stages 8 input rows (jy4*4-2 .. jy4*4+5) into
// guard-padded LDS, produces 16 output rows. Interior threads use pure
// constant weights; renormalization only on divergent edge branches.

#define Hin 256
#define Win 256

#define WK00 -0.0439453125f
#define WK01  0.3896484375f
#define WK02  0.7275390625f
#define WK03 -0.0732421875f
#define WK10 -0.0068359375f
#define WK11  0.0908203125f
#define WK12  0.9638671875f
#define WK13 -0.0478515625f

__global__ __launch_bounds__(256, 4) void cubic_up4(const float* __restrict__ in,
                                                    float* __restrict__ out) {
    const int jx = threadIdx.x;          // input column 0..255
    const int jy4 = blockIdx.x & 63;     // row group (4 input rows)
    const int bc = blockIdx.x >> 6;      // batch*channel 0..47
    const int jy0 = jy4 << 2;

    const float* __restrict__ inp = in + (size_t)bc * (Hin * Win);
    float* __restrict__ outp = out + (size_t)bc * ((size_t)Hin * Win * 16);

    const float WK[4][4] = {{WK00, WK01, WK02, WK03},
                            {WK10, WK11, WK12, WK13},
                            {WK13, WK12, WK11, WK10},
                            {WK03, WK02, WK01, WK00}};

    // ---- stage rows jy0-2 .. jy0+5 into guard-padded LDS ----
    __shared__ float sv[8][Win + 4];
#pragma unroll
    for (int r = 0; r < 8; ++r) {
        int ry = jy0 - 2 + r;
        ry = ry < 0 ? 0 : (ry > Hin - 1 ? Hin - 1 : ry);  // OOB rows: weight 0
        sv[r][jx + 2] = inp[ry * Win + jx];
    }
    if (jx < 2) {
#pragma unroll
        for (int r = 0; r < 8; ++r) sv[r][jx] = 0.f;       // left guards
    }
    if (jx >= Win - 2) {
#pragma unroll
        for (int r = 0; r < 8; ++r) sv[r][jx + 4] = 0.f;   // right guards
    }
    __syncthreads();

    // ---- horizontal pass: 8 rows x 4 phases ----
    float h[8][4];
    const bool xedge = (jx < 2) | (jx >= Win - 2);
    if (!xedge) {
#pragma unroll
        for (int r = 0; r < 8; ++r) {
            const float* p = &sv[r][jx];
            const float a0 = p[0], a1 = p[1], a2 = p[2], a3 = p[3], a4 = p[4];
            h[r][0] = WK00 * a0 + WK01 * a1 + WK02 * a2 + WK03 * a3;
            h[r][1] = WK10 * a0 + WK11 * a1 + WK12 * a2 + WK13 * a3;
            h[r][2] = WK13 * a1 + WK12 * a2 + WK11 * a3 + WK10 * a4;
            h[r][3] = WK03 * a1 + WK02 * a2 + WK01 * a3 + WK00 * a4;
        }
    } else {
        // edge columns: drop OOB taps, renormalize (fast rcp is plenty accurate)
        float wx[4][4];
#pragma unroll
        for (int r = 0; r < 4; ++r) {
            const int o = r >> 1;
            float s = 0.f;
#pragma unroll
            for (int t = 0; t < 4; ++t) {
                const int c = jx - 2 + o + t;
                const float w = (c >= 0 && c < Win) ? WK[r][t] : 0.f;
                wx[r][t] = w;
                s += w;
            }
            const float inv = __builtin_amdgcn_rcpf(s);
#pragma unroll
            for (int t = 0; t < 4; ++t) wx[r][t] *= inv;
        }
#pragma unroll
        for (int r = 0; r < 8; ++r) {
            const float* p = &sv[r][jx];  // dropped taps hit zeroed guards
#pragma unroll
            for (int rx = 0; rx < 4; ++rx) {
                const int o = rx >> 1;
                h[r][rx] = wx[rx][0] * p[o] + wx[rx][1] * p[o + 1] +
                           wx[rx][2] * p[o + 2] + wx[rx][3] * p[o + 3];
            }
        }
    }

    // ---- vertical pass + stores: 4 input rows x 4 phases ----
    const bool yedge = (jy4 == 0) | (jy4 == 63);
    if (!yedge) {
#pragma unroll
        for (int ty = 0; ty < 4; ++ty) {
#pragma unroll
            for (int ry = 0; ry < 4; ++ry) {
                const int o = ty + (ry >> 1);
                float4 res;
                float* rp = (float*)&res;
#pragma unroll
                for (int rx = 0; rx < 4; ++rx) {
                    rp[rx] = WK[ry][0] * h[o][rx] + WK[ry][1] * h[o + 1][rx] +
                             WK[ry][2] * h[o + 2][rx] + WK[ry][3] * h[o + 3][rx];
                }
                *(float4*)(outp + (size_t)((jy4 << 4) + (ty << 2) + ry) * (Win * 4) +
                           (jx << 2)) = res;
            }
        }
    } else {
#pragma unroll
        for (int ty = 0; ty < 4; ++ty) {
            const int jy = jy0 + ty;
            float wy[4][4];
#pragma unroll
            for (int r = 0; r < 4; ++r) {
                const int o = r >> 1;
                float s = 0.f;
#pragma unroll
                for (int t = 0; t < 4; ++t) {
                    const int c = jy - 2 + o + t;
                    const float w = (c >= 0 && c < Hin) ? WK[r][t] : 0.f;
                    wy[r][t] = w;
                    s += w;
                }
                const float inv = __builtin_amdgcn_rcpf(s);
#pragma unroll
                for (int t = 0; t < 4; ++t) wy[r][t] *= inv;
            }
#pragma unroll
            for (int ry = 0; ry < 4; ++ry) {
                const int o = ty + (ry >> 1);
                float4 res;
                float* rp = (float*)&res;
#pragma unroll
                for (int rx = 0; rx < 4; ++rx) {
                    rp[rx] = wy[ry][0] * h[o][rx] + wy[ry][1] * h[o + 1][rx] +
                             wy[ry][2] * h[o + 2][rx] + wy[ry][3] * h[o + 3][rx];
                }
                *(float4*)(outp + (size_t)((jy4 << 4) + (ty << 2) + ry) * (Win * 4) +
                           (jx << 2)) = res;
            }
        }
    }
}

extern "C" void kernel_launch(void* const* d_in, const int* in_sizes, int n_in,
                              void* d_out, int out_size, void* d_ws, size_t ws_size,
                              hipStream_t stream) {
    const float* x = (const float*)d_in[0];
    float* out = (float*)d_out;
    // 48 (b*c) * 64 row-groups = 3072 blocks, 256 threads.
    cubic_up4<<<dim3(48 * 64), dim3(256), 0, stream>>>(x, out);
}